// Round 14
// baseline (640.440 us; speedup 1.0000x reference)
//
#include <hip/hip_runtime.h>
#include <math.h>

#define N_NODES  100000
#define N_EDGES  3200000
#define K_IN     1433
#define NH       16
#define NO       7

#define TK       16
#define KSPLIT   9
#define CPS      10                           // chunks per split (9*10*16 = 1440 >= 1433)
#define RW       (CPS * TK)                   // 160 W1 rows per split
#define TILE_R   128                          // rows per wave-tile
#define SXS      20                           // X-tile row stride (floats): 80B, 16B-aligned
#define NTILEV   ((N_NODES + TILE_R - 1) / TILE_R)   // 782
#define NRBV     ((NTILEV + 3) / 4)                  // 196 row-blocks (4 waves/block)
#define SLOT     96                           // adjacency slots per node
#define GREP     3                            // gemm1 probe repeats (R14 probe)

#define NBKT     256
#define BKN      391                          // 256*391 = 100096 >= N_NODES
#define SBLK     512
#define EPB      ((N_EDGES + SBLK - 1) / SBLK)    // 6250 edges/block

typedef float f4  __attribute__((ext_vector_type(4)));
typedef float f4u __attribute__((ext_vector_type(4), aligned(4)));

// ---------------- B1: per-block bucket histogram of key[] ----------------
__global__ __launch_bounds__(256)
void k_pcount(const int* __restrict__ key, int* __restrict__ partial) {
    __shared__ int lh[NBKT];
    lh[threadIdx.x] = 0;
    __syncthreads();
    const int e0 = blockIdx.x * EPB;
    const int e1 = min(e0 + EPB, N_EDGES);
    for (int i = e0 + threadIdx.x; i < e1; i += 256)
        atomicAdd(&lh[key[i] / BKN], 1);
    __syncthreads();
    partial[blockIdx.x * NBKT + threadIdx.x] = lh[threadIdx.x];
}

// ---------------- B2: per-bucket exclusive scan of partials over blocks ----
__global__ __launch_bounds__(256)
void k_colscan(const int* __restrict__ partial, int* __restrict__ pbase,
               int* __restrict__ btot) {
    __shared__ int s[256];
    const int b = blockIdx.x, t = threadIdx.x;
    const int v0 = partial[(2 * t)     * NBKT + b];
    const int v1 = partial[(2 * t + 1) * NBKT + b];
    const int pair = v0 + v1;
    s[t] = pair;
    __syncthreads();
    for (int o = 1; o < 256; o <<= 1) {
        int u = (t >= o) ? s[t - o] : 0;
        __syncthreads();
        s[t] += u;
        __syncthreads();
    }
    const int excl = s[t] - pair;
    pbase[(2 * t)     * NBKT + b] = excl;
    pbase[(2 * t + 1) * NBKT + b] = excl + v0;
    if (t == 255) btot[b] = s[255];
}

// ---------------- B3: exclusive scan of bucket totals (both keys) ----------
__global__ __launch_bounds__(256)
void k_basescan(const int* __restrict__ btd, int* __restrict__ bbd,
                const int* __restrict__ bts, int* __restrict__ bbs) {
    __shared__ int s[256];
    const int t = threadIdx.x;
    int v = btd[t];
    s[t] = v;
    __syncthreads();
    for (int o = 1; o < 256; o <<= 1) {
        int u = (t >= o) ? s[t - o] : 0;
        __syncthreads();
        s[t] += u;
        __syncthreads();
    }
    bbd[t] = s[t] - v;
    __syncthreads();
    v = bts[t];
    s[t] = v;
    __syncthreads();
    for (int o = 1; o < 256; o <<= 1) {
        int u = (t >= o) ? s[t - o] : 0;
        __syncthreads();
        s[t] += u;
        __syncthreads();
    }
    bbs[t] = s[t] - v;
}

// ---------------- B4a: scatter (src,dst) pairs bucketed by dst -------------
__global__ __launch_bounds__(256)
void k_pscatter2(const int* __restrict__ src, const int* __restrict__ dst,
                 const int* __restrict__ pbase, const int* __restrict__ bbase,
                 int2* __restrict__ ebuf) {
    __shared__ int lh[NBKT];
    __shared__ int lb[NBKT];
    const int t = threadIdx.x;
    lh[t] = 0;
    lb[t] = bbase[t] + pbase[blockIdx.x * NBKT + t];
    __syncthreads();
    const int e0 = blockIdx.x * EPB;
    const int e1 = min(e0 + EPB, N_EDGES);
    for (int i = e0 + t; i < e1; i += 256) {
        int sv = src[i], dv = dst[i];
        int b = dv / BKN;
        int p = lb[b] + atomicAdd(&lh[b], 1);
        ebuf[p] = make_int2(sv, dv);
    }
}

// ---------------- B4b: scatter src values bucketed by src ------------------
__global__ __launch_bounds__(256)
void k_pscatter1(const int* __restrict__ src, const int* __restrict__ pbase,
                 const int* __restrict__ bbase, int* __restrict__ sbuf) {
    __shared__ int lh[NBKT];
    __shared__ int lb[NBKT];
    const int t = threadIdx.x;
    lh[t] = 0;
    lb[t] = bbase[t] + pbase[blockIdx.x * NBKT + t];
    __syncthreads();
    const int e0 = blockIdx.x * EPB;
    const int e1 = min(e0 + EPB, N_EDGES);
    for (int i = e0 + t; i < e1; i += 256) {
        int sv = src[i];
        int b = sv / BKN;
        int p = lb[b] + atomicAdd(&lh[b], 1);
        sbuf[p] = sv;
    }
}

// ---------------- B5a: per-bucket adj build + exact cnt (LDS cursors) ------
__global__ __launch_bounds__(512)
void k_adj(const int2* __restrict__ ebuf, const int* __restrict__ bbase,
           const int* __restrict__ btot, int* __restrict__ adj,
           int* __restrict__ cnt) {
    __shared__ int cur[BKN];
    const int b = blockIdx.x;
    for (int i = threadIdx.x; i < BKN; i += 512) cur[i] = 0;
    __syncthreads();
    const int s0 = bbase[b], s1 = s0 + btot[b];
    const int nb = b * BKN;
    for (int i = s0 + threadIdx.x; i < s1; i += 512) {
        int2 e = ebuf[i];
        int p = atomicAdd(&cur[e.y - nb], 1);
        if (p < SLOT) adj[e.y * SLOT + p] = e.x;
    }
    __syncthreads();
    for (int i = threadIdx.x; i < BKN; i += 512) {
        int n = nb + i;
        if (n < N_NODES) cnt[n] = cur[i];
    }
}

// ---------------- B5b: per-bucket src histogram -> deg_out ------------------
__global__ __launch_bounds__(512)
void k_hist(const int* __restrict__ sbuf, const int* __restrict__ bbase,
            const int* __restrict__ btot, int* __restrict__ deg) {
    __shared__ int cur[BKN];
    const int b = blockIdx.x;
    for (int i = threadIdx.x; i < BKN; i += 512) cur[i] = 0;
    __syncthreads();
    const int s0 = bbase[b], s1 = s0 + btot[b];
    const int nb = b * BKN;
    for (int i = s0 + threadIdx.x; i < s1; i += 512)
        atomicAdd(&cur[sbuf[i] - nb], 1);
    __syncthreads();
    for (int i = threadIdx.x; i < BKN; i += 512) {
        int n = nb + i;
        if (n < N_NODES) deg[n] = cur[i];
    }
}

// ---------------- K2: hpart[split] = X[:, ksplit] @ W1[ksplit, :] ----------
// R14 PROBE: body repeated GREP times (deterministic, same output) so the
// dispatch exceeds the 338us harness fills and its counters surface in top-5.

#define LOADG(KN, S0,S1,S2,S3,S4,S5,S6,S7)                               \
  { if ((KN) + TK <= K_IN) {                                             \
      S0 = *(const f4u*)(xp0 + (KN)); S1 = *(const f4u*)(xp1 + (KN));    \
      S2 = *(const f4u*)(xp2 + (KN)); S3 = *(const f4u*)(xp3 + (KN));    \
      S4 = *(const f4u*)(xp4 + (KN)); S5 = *(const f4u*)(xp5 + (KN));    \
      S6 = *(const f4u*)(xp6 + (KN)); S7 = *(const f4u*)(xp7 + (KN));    \
    } else {                                                             \
      S0=0.f;S1=0.f;S2=0.f;S3=0.f;S4=0.f;S5=0.f;S6=0.f;S7=0.f;           \
      if (Lq < 2) {                                                      \
        S0 = *(const f4u*)(xp0 + (KN)); S1 = *(const f4u*)(xp1 + (KN));  \
        S2 = *(const f4u*)(xp2 + (KN)); S3 = *(const f4u*)(xp3 + (KN));  \
        S4 = *(const f4u*)(xp4 + (KN)); S5 = *(const f4u*)(xp5 + (KN));  \
        S6 = *(const f4u*)(xp6 + (KN)); S7 = *(const f4u*)(xp7 + (KN));  \
      } else if (Lq == 2) {                                              \
        S0[0] = xp0[(KN)]; S1[0] = xp1[(KN)];                            \
        S2[0] = xp2[(KN)]; S3[0] = xp3[(KN)];                            \
        S4[0] = xp4[(KN)]; S5[0] = xp5[(KN)];                            \
        S6[0] = xp6[(KN)]; S7[0] = xp7[(KN)];                            \
      }                                                                  \
    } }

#define WRITE_SET(S0,S1,S2,S3,S4,S5,S6,S7)                               \
  { *(f4*)(xbw + 0*16*SXS) = S0; *(f4*)(xbw + 1*16*SXS) = S1;            \
    *(f4*)(xbw + 2*16*SXS) = S2; *(f4*)(xbw + 3*16*SXS) = S3;            \
    *(f4*)(xbw + 4*16*SXS) = S4; *(f4*)(xbw + 5*16*SXS) = S5;            \
    *(f4*)(xbw + 6*16*SXS) = S6; *(f4*)(xbw + 7*16*SXS) = S7; }

#define READ_FMA(CC)                                                     \
  { f4 xa0 = *(const f4*)(xra +  0), xa1 = *(const f4*)(xra +  4);       \
    f4 xa2 = *(const f4*)(xra +  8), xa3 = *(const f4*)(xra + 12);       \
    f4 xb0 = *(const f4*)(xrb +  0), xb1 = *(const f4*)(xrb +  4);       \
    f4 xb2 = *(const f4*)(xrb +  8), xb3 = *(const f4*)(xrb + 12);       \
    const float* wb = wlds + (CC) * (TK * NH);                           \
    _Pragma("unroll")                                                    \
    for (int kk = 0; kk < TK; ++kk) {                                    \
      const f4 va = (kk < 4) ? xa0 : (kk < 8) ? xa1 : (kk < 12) ? xa2 : xa3; \
      const f4 vb = (kk < 4) ? xb0 : (kk < 8) ? xb1 : (kk < 12) ? xb2 : xb3; \
      const float xa = va[kk & 3], xb = vb[kk & 3];                      \
      const f4* wr = (const f4*)(wb + kk * NH);                          \
      const f4 w0 = wr[0], w1 = wr[1], w2 = wr[2], w3 = wr[3];           \
      accA0 += xa * w0; accA1 += xa * w1; accA2 += xa * w2; accA3 += xa * w3; \
      accB0 += xb * w0; accB1 += xb * w1; accB2 += xb * w2; accB3 += xb * w3; \
    } }

__global__ __launch_bounds__(256)
void k_gemm1(const float* __restrict__ X, const float* __restrict__ W1,
             float* __restrict__ hpart) {
    __shared__ float wlds[RW * NH];                 // 10240 B
    __shared__ float sX[4][TILE_R * SXS];           // 4 x 10240 B
    const int wid = threadIdx.x >> 6;
    const int t   = threadIdx.x & 63;
    const int rb    = blockIdx.x % NRBV;
    const int split = blockIdx.x / NRBV;

    {
        const f4* W1v = (const f4*)W1;              // each W1 row = 4 f4
        const int wbase = split * RW;
#pragma unroll
        for (int r = 0; r < 3; ++r) {               // ceil(640/256) = 3 iters
            int idx = r * 256 + threadIdx.x;        // f4 index into wlds
            if (idx < RW * 4) {
                int krow = wbase + (idx >> 2);
                f4 wv = 0.f;
                if (krow < K_IN) wv = W1v[krow * 4 + (idx & 3)];
                ((f4*)wlds)[idx] = wv;
            }
        }
    }
    __syncthreads();

    const int tile = rb * 4 + wid;
    if (tile >= NTILEV) return;                     // wave-uniform, after sync
    const int base = tile * TILE_R;
    const int Lq = t & 3;                           // 16B granule within 64B
    const int Lr = t >> 2;                          // row group 0..15

    const float* xp0 = X + (size_t)min(base + Lr +   0, N_NODES - 1) * K_IN + 4 * Lq;
    const float* xp1 = X + (size_t)min(base + Lr +  16, N_NODES - 1) * K_IN + 4 * Lq;
    const float* xp2 = X + (size_t)min(base + Lr +  32, N_NODES - 1) * K_IN + 4 * Lq;
    const float* xp3 = X + (size_t)min(base + Lr +  48, N_NODES - 1) * K_IN + 4 * Lq;
    const float* xp4 = X + (size_t)min(base + Lr +  64, N_NODES - 1) * K_IN + 4 * Lq;
    const float* xp5 = X + (size_t)min(base + Lr +  80, N_NODES - 1) * K_IN + 4 * Lq;
    const float* xp6 = X + (size_t)min(base + Lr +  96, N_NODES - 1) * K_IN + 4 * Lq;
    const float* xp7 = X + (size_t)min(base + Lr + 112, N_NODES - 1) * K_IN + 4 * Lq;

    float* xbuf = sX[wid];
    float* xbw  = xbuf + Lr * SXS + 4 * Lq;         // write base (granule 0)
    const float* xra = xbuf + t * SXS;              // read row t
    const float* xrb = xbuf + (t + 64) * SXS;       // read row t+64

    const size_t sb = (size_t)split * N_NODES;
    const int k0 = split * RW;                      // first k of this split

#pragma unroll 1
    for (int rep = 0; rep < GREP; ++rep) {
        asm volatile("" ::: "memory");              // no cross-rep CSE

        f4 accA0 = 0.f, accA1 = 0.f, accA2 = 0.f, accA3 = 0.f;
        f4 accB0 = 0.f, accB1 = 0.f, accB2 = 0.f, accB3 = 0.f;

        f4 sP0, sP1, sP2, sP3, sP4, sP5, sP6, sP7;  // named stage sets
        f4 sQ0, sQ1, sQ2, sQ3, sQ4, sQ5, sQ6, sQ7;

        LOADG(k0, sP0, sP1, sP2, sP3, sP4, sP5, sP6, sP7)

#pragma unroll 1
        for (int j = 0; j < CPS / 2; ++j) {
            const int ke = k0 + 2 * j * TK;         // even chunk k-offset
            WRITE_SET(sP0, sP1, sP2, sP3, sP4, sP5, sP6, sP7)
            LOADG(ke + TK, sQ0, sQ1, sQ2, sQ3, sQ4, sQ5, sQ6, sQ7)
            __builtin_amdgcn_wave_barrier();
            READ_FMA(2 * j)
            __builtin_amdgcn_wave_barrier();
            WRITE_SET(sQ0, sQ1, sQ2, sQ3, sQ4, sQ5, sQ6, sQ7)
            if (j + 1 < CPS / 2) {
                LOADG(ke + 2 * TK, sP0, sP1, sP2, sP3, sP4, sP5, sP6, sP7)
            }
            __builtin_amdgcn_wave_barrier();
            READ_FMA(2 * j + 1)
            __builtin_amdgcn_wave_barrier();
        }

        if (base + t < N_NODES) {
            f4* hp = (f4*)(hpart + (sb + base + t) * NH);
            hp[0] = accA0; hp[1] = accA1; hp[2] = accA2; hp[3] = accA3;
        }
        if (base + 64 + t < N_NODES) {
            f4* hp = (f4*)(hpart + (sb + base + 64 + t) * NH);
            hp[0] = accB0; hp[1] = accB1; hp[2] = accB2; hp[3] = accB3;
        }
    }
}

// ---------------- K3: h = norm_src * sum_s hpart[s] ----------------
__global__ __launch_bounds__(256)
void k_reduce(const float* __restrict__ hpart, const int* __restrict__ deg_out,
              float* __restrict__ h) {
    int idx = blockIdx.x * 256 + threadIdx.x;   // f4 index
    if (idx >= N_NODES * 4) return;
    f4 a = 0.f;
#pragma unroll
    for (int s = 0; s < KSPLIT; ++s)
        a += ((const f4*)hpart)[(size_t)s * N_NODES * 4 + idx];
    float ns = rsqrtf((float)max(deg_out[idx >> 2], 1));
    ((f4*)h)[idx] = a * ns;
}

// ---------------- K4: gather layer1 + relu + fused (.. @ W2) ----------------
__global__ __launch_bounds__(256)
void k_layer1(const float* __restrict__ h, const int* __restrict__ adj,
              const int* __restrict__ cnt, const int* __restrict__ deg_out,
              const float* __restrict__ W2, const float* __restrict__ b1,
              float* __restrict__ g) {
    const int lane = threadIdx.x & 63;
    const int wid  = threadIdx.x >> 6;
    const int d    = blockIdx.x * 4 + wid;
    if (d >= N_NODES) return;                  // wave-uniform
    const int j4 = lane & 3, slot = lane >> 2;
    const int start = d * SLOT;
    const int deg   = min(cnt[d], SLOT);
    const int end   = start + deg;
    f4 agg = 0.f;
    for (int p = start + slot; p < end; p += 16) {
        int s = adj[p];
        agg += ((const f4*)h)[s * 4 + j4];
    }
#pragma unroll
    for (int off = 4; off < 64; off <<= 1) {
        agg[0] += __shfl_xor(agg[0], off);
        agg[1] += __shfl_xor(agg[1], off);
        agg[2] += __shfl_xor(agg[2], off);
        agg[3] += __shfl_xor(agg[3], off);
    }
    __shared__ float st[4][NH];
    const float nd = rsqrtf((float)max(deg, 1));
    if (slot == 0) {
        f4 bb = ((const f4*)b1)[j4];
        f4 tj;
        tj[0] = fmaxf(fmaf(agg[0], nd, bb[0]), 0.f);
        tj[1] = fmaxf(fmaf(agg[1], nd, bb[1]), 0.f);
        tj[2] = fmaxf(fmaf(agg[2], nd, bb[2]), 0.f);
        tj[3] = fmaxf(fmaf(agg[3], nd, bb[3]), 0.f);
        ((f4*)st[wid])[j4] = tj;
    }
    __builtin_amdgcn_wave_barrier();
    float r = 0.f;
    if (lane < NO) {
#pragma unroll
        for (int qq = 0; qq < NH; ++qq)
            r = fmaf(st[wid][qq], W2[qq * NO + lane], r);
    }
    if (lane < 8) {
        float ns = rsqrtf((float)max(deg_out[d], 1));
        g[(size_t)d * 8 + lane] = (lane < NO) ? ns * r : 0.f;  // zero pad slot
    }
}

// ---------------- K5: gather layer2 -> out ----------------
__global__ __launch_bounds__(256)
void k_layer2(const float* __restrict__ g, const int* __restrict__ adj,
              const int* __restrict__ cnt, const float* __restrict__ b2,
              float* __restrict__ out) {
    const int lane = threadIdx.x & 63;
    const int wid  = threadIdx.x >> 6;
    const int d    = blockIdx.x * 4 + wid;
    if (d >= N_NODES) return;
    const int o4 = lane & 1, slot = lane >> 1;
    const int start = d * SLOT;
    const int deg   = min(cnt[d], SLOT);
    const int end   = start + deg;
    f4 agg = 0.f;
    for (int p = start + slot; p < end; p += 32) {
        int s = adj[p];
        agg += ((const f4*)g)[s * 2 + o4];
    }
#pragma unroll
    for (int off = 2; off < 64; off <<= 1) {
        agg[0] += __shfl_xor(agg[0], off);
        agg[1] += __shfl_xor(agg[1], off);
        agg[2] += __shfl_xor(agg[2], off);
        agg[3] += __shfl_xor(agg[3], off);
    }
    // even lanes hold o=0..3 sums, odd lanes hold o=4..7 sums
    const int sl = lane >> 2;
    float v0 = __shfl(agg[0], sl);
    float v1 = __shfl(agg[1], sl);
    float v2 = __shfl(agg[2], sl);
    float v3 = __shfl(agg[3], sl);
    int cm = lane & 3;
    float v = (cm == 0) ? v0 : (cm == 1) ? v1 : (cm == 2) ? v2 : v3;
    if (lane < NO) {
        float nd = rsqrtf((float)max(deg, 1));
        out[(size_t)d * NO + lane] = fmaf(v, nd, b2[lane]);
    }
}

extern "C" void kernel_launch(void* const* d_in, const int* in_sizes, int n_in,
                              void* d_out, int out_size, void* d_ws, size_t ws_size,
                              hipStream_t stream) {
    const float* X   = (const float*)d_in[0];
    const int*   src = (const int*)d_in[1];
    const int*   dst = (const int*)d_in[2];
    const float* W1  = (const float*)d_in[3];
    const float* b1  = (const float*)d_in[4];
    const float* W2  = (const float*)d_in[5];
    const float* b2  = (const float*)d_in[6];
    float* out = (float*)d_out;

    char* w = (char*)d_ws;
    float* hpart    = (float*)w;  w += (size_t)KSPLIT * N_NODES * NH * 4; // 57.6 MB
    float* h        = (float*)w;  w += (size_t)N_NODES * NH * 4;          // 6.4 MB
    float* g        = (float*)w;  w += (size_t)N_NODES * 8 * 4;           // 3.2 MB
    int*   adj      = (int*)w;    w += (size_t)N_NODES * SLOT * 4;        // 38.4 MB
    int*   deg_out_a= (int*)w;    w += (size_t)N_NODES * 4;
    int*   cnt      = (int*)w;    w += (size_t)N_NODES * 4;
    int2*  ebuf     = (int2*)w;   w += (size_t)N_EDGES * 8;               // 25.6 MB
    int*   sbuf     = (int*)w;    w += (size_t)N_EDGES * 4;               // 12.8 MB
    int*   partial_d= (int*)w;    w += (size_t)SBLK * NBKT * 4;           // 512 KB
    int*   partial_s= (int*)w;    w += (size_t)SBLK * NBKT * 4;
    int*   pbase_d  = (int*)w;    w += (size_t)SBLK * NBKT * 4;
    int*   pbase_s  = (int*)w;    w += (size_t)SBLK * NBKT * 4;
    int*   btot_d   = (int*)w;    w += NBKT * 4;
    int*   btot_s   = (int*)w;    w += NBKT * 4;
    int*   bbase_d  = (int*)w;    w += NBKT * 4;
    int*   bbase_s  = (int*)w;    w += NBKT * 4;

    // ---- atomic-free graph build (counting sort by 391-node buckets) ----
    k_pcount   <<<SBLK, 256, 0, stream>>>(dst, partial_d);
    k_pcount   <<<SBLK, 256, 0, stream>>>(src, partial_s);
    k_colscan  <<<NBKT, 256, 0, stream>>>(partial_d, pbase_d, btot_d);
    k_colscan  <<<NBKT, 256, 0, stream>>>(partial_s, pbase_s, btot_s);
    k_basescan <<<1,    256, 0, stream>>>(btot_d, bbase_d, btot_s, bbase_s);
    k_pscatter2<<<SBLK, 256, 0, stream>>>(src, dst, pbase_d, bbase_d, ebuf);
    k_pscatter1<<<SBLK, 256, 0, stream>>>(src, pbase_s, bbase_s, sbuf);
    k_adj      <<<NBKT, 512, 0, stream>>>(ebuf, bbase_d, btot_d, adj, cnt);
    k_hist     <<<NBKT, 512, 0, stream>>>(sbuf, bbase_s, btot_s, deg_out_a);

    // ---- GCN pipeline (gemm1 carries the x3 probe repeat this round) ----
    k_gemm1 <<<NRBV * KSPLIT, 256, 0, stream>>>(X, W1, hpart);
    k_reduce<<<(N_NODES * 4 + 255) / 256, 256, 0, stream>>>(hpart, deg_out_a, h);
    k_layer1<<<(N_NODES + 3) / 4, 256, 0, stream>>>(h, adj, cnt, deg_out_a,
                                                    W2, b1, g);
    k_layer2<<<(N_NODES + 3) / 4, 256, 0, stream>>>(g, adj, cnt, b2, out);
}

// Round 15
// 390.829 us; speedup vs baseline: 1.6387x; 1.6387x over previous
//
#include <hip/hip_runtime.h>
#include <math.h>

#define N_NODES  100000
#define N_EDGES  3200000
#define K_IN     1433
#define NH       16
#define NO       7

#define TK       16
#define KSPLIT   9
#define CPS      10                           // chunks per split (9*10*16 = 1440 >= 1433)
#define RW       (CPS * TK)                   // 160 W1 rows per split
#define TILE_R   128                          // rows per wave-tile
#define SXS      20                           // X-tile row stride (floats): 80B, 16B-aligned
#define NTILEV   ((N_NODES + TILE_R - 1) / TILE_R)   // 782
#define NRBV     ((NTILEV + 3) / 4)                  // 196 row-blocks (4 waves/block)
#define SLOT     96                           // adjacency slots per node

#define NBKT     256
#define BKN      391                          // 256*391 = 100096 >= N_NODES
#define SBLK     512
#define EPB      ((N_EDGES + SBLK - 1) / SBLK)    // 6250 edges/block

typedef float f4  __attribute__((ext_vector_type(4)));
typedef float f4u __attribute__((ext_vector_type(4), aligned(4)));

// ---------------- B1: per-block bucket histogram of key[] ----------------
__global__ __launch_bounds__(256)
void k_pcount(const int* __restrict__ key, int* __restrict__ partial) {
    __shared__ int lh[NBKT];
    lh[threadIdx.x] = 0;
    __syncthreads();
    const int e0 = blockIdx.x * EPB;
    const int e1 = min(e0 + EPB, N_EDGES);
    for (int i = e0 + threadIdx.x; i < e1; i += 256)
        atomicAdd(&lh[key[i] / BKN], 1);
    __syncthreads();
    partial[blockIdx.x * NBKT + threadIdx.x] = lh[threadIdx.x];
}

// ---------------- B2: per-bucket exclusive scan of partials over blocks ----
__global__ __launch_bounds__(256)
void k_colscan(const int* __restrict__ partial, int* __restrict__ pbase,
               int* __restrict__ btot) {
    __shared__ int s[256];
    const int b = blockIdx.x, t = threadIdx.x;
    const int v0 = partial[(2 * t)     * NBKT + b];
    const int v1 = partial[(2 * t + 1) * NBKT + b];
    const int pair = v0 + v1;
    s[t] = pair;
    __syncthreads();
    for (int o = 1; o < 256; o <<= 1) {
        int u = (t >= o) ? s[t - o] : 0;
        __syncthreads();
        s[t] += u;
        __syncthreads();
    }
    const int excl = s[t] - pair;
    pbase[(2 * t)     * NBKT + b] = excl;
    pbase[(2 * t + 1) * NBKT + b] = excl + v0;
    if (t == 255) btot[b] = s[255];
}

// ---------------- B3: exclusive scan of bucket totals (both keys) ----------
__global__ __launch_bounds__(256)
void k_basescan(const int* __restrict__ btd, int* __restrict__ bbd,
                const int* __restrict__ bts, int* __restrict__ bbs) {
    __shared__ int s[256];
    const int t = threadIdx.x;
    int v = btd[t];
    s[t] = v;
    __syncthreads();
    for (int o = 1; o < 256; o <<= 1) {
        int u = (t >= o) ? s[t - o] : 0;
        __syncthreads();
        s[t] += u;
        __syncthreads();
    }
    bbd[t] = s[t] - v;
    __syncthreads();
    v = bts[t];
    s[t] = v;
    __syncthreads();
    for (int o = 1; o < 256; o <<= 1) {
        int u = (t >= o) ? s[t - o] : 0;
        __syncthreads();
        s[t] += u;
        __syncthreads();
    }
    bbs[t] = s[t] - v;
}

// ---------------- B4a: scatter (src,dst) pairs bucketed by dst -------------
__global__ __launch_bounds__(256)
void k_pscatter2(const int* __restrict__ src, const int* __restrict__ dst,
                 const int* __restrict__ pbase, const int* __restrict__ bbase,
                 int2* __restrict__ ebuf) {
    __shared__ int lh[NBKT];
    __shared__ int lb[NBKT];
    const int t = threadIdx.x;
    lh[t] = 0;
    lb[t] = bbase[t] + pbase[blockIdx.x * NBKT + t];
    __syncthreads();
    const int e0 = blockIdx.x * EPB;
    const int e1 = min(e0 + EPB, N_EDGES);
    for (int i = e0 + t; i < e1; i += 256) {
        int sv = src[i], dv = dst[i];
        int b = dv / BKN;
        int p = lb[b] + atomicAdd(&lh[b], 1);
        ebuf[p] = make_int2(sv, dv);
    }
}

// ---------------- B4b: scatter src values bucketed by src ------------------
__global__ __launch_bounds__(256)
void k_pscatter1(const int* __restrict__ src, const int* __restrict__ pbase,
                 const int* __restrict__ bbase, int* __restrict__ sbuf) {
    __shared__ int lh[NBKT];
    __shared__ int lb[NBKT];
    const int t = threadIdx.x;
    lh[t] = 0;
    lb[t] = bbase[t] + pbase[blockIdx.x * NBKT + t];
    __syncthreads();
    const int e0 = blockIdx.x * EPB;
    const int e1 = min(e0 + EPB, N_EDGES);
    for (int i = e0 + t; i < e1; i += 256) {
        int sv = src[i];
        int b = sv / BKN;
        int p = lb[b] + atomicAdd(&lh[b], 1);
        sbuf[p] = sv;
    }
}

// ---------------- B5a: per-bucket adj build + exact cnt (LDS cursors) ------
__global__ __launch_bounds__(512)
void k_adj(const int2* __restrict__ ebuf, const int* __restrict__ bbase,
           const int* __restrict__ btot, int* __restrict__ adj,
           int* __restrict__ cnt) {
    __shared__ int cur[BKN];
    const int b = blockIdx.x;
    for (int i = threadIdx.x; i < BKN; i += 512) cur[i] = 0;
    __syncthreads();
    const int s0 = bbase[b], s1 = s0 + btot[b];
    const int nb = b * BKN;
    for (int i = s0 + threadIdx.x; i < s1; i += 512) {
        int2 e = ebuf[i];
        int p = atomicAdd(&cur[e.y - nb], 1);
        if (p < SLOT) adj[e.y * SLOT + p] = e.x;
    }
    __syncthreads();
    for (int i = threadIdx.x; i < BKN; i += 512) {
        int n = nb + i;
        if (n < N_NODES) cnt[n] = cur[i];
    }
}

// ---------------- B5b: per-bucket src histogram -> deg_out ------------------
__global__ __launch_bounds__(512)
void k_hist(const int* __restrict__ sbuf, const int* __restrict__ bbase,
            const int* __restrict__ btot, int* __restrict__ deg) {
    __shared__ int cur[BKN];
    const int b = blockIdx.x;
    for (int i = threadIdx.x; i < BKN; i += 512) cur[i] = 0;
    __syncthreads();
    const int s0 = bbase[b], s1 = s0 + btot[b];
    const int nb = b * BKN;
    for (int i = s0 + threadIdx.x; i < s1; i += 512)
        atomicAdd(&cur[sbuf[i] - nb], 1);
    __syncthreads();
    for (int i = threadIdx.x; i < BKN; i += 512) {
        int n = nb + i;
        if (n < N_NODES) deg[n] = cur[i];
    }
}

// ---------------- K2: hpart[split] = X[:, ksplit] @ W1[ksplit, :] ----------
// R15: j-quad split across lanes. R14 probe showed the LDS pipe bound by 64
// W-broadcast ds_read_b128 per chunk-wave (VALUBusy 26.5%, occ 11.4%). Lane
// (rg=t>>2, jq=t&3) computes 8 rows x its own j-quad: per chunk-wave the LDS
// issues drop 80 -> 56 (W 64->16; x 8->32 but 4-way broadcast, 2-way banks
// = free), putting LDS (~77us) under the 91us HBM floor. Staging unchanged.

#define LOADG(KN, S0,S1,S2,S3,S4,S5,S6,S7)                               \
  { if ((KN) + TK <= K_IN) {                                             \
      S0 = *(const f4u*)(xp0 + (KN)); S1 = *(const f4u*)(xp1 + (KN));    \
      S2 = *(const f4u*)(xp2 + (KN)); S3 = *(const f4u*)(xp3 + (KN));    \
      S4 = *(const f4u*)(xp4 + (KN)); S5 = *(const f4u*)(xp5 + (KN));    \
      S6 = *(const f4u*)(xp6 + (KN)); S7 = *(const f4u*)(xp7 + (KN));    \
    } else {                                                             \
      S0=0.f;S1=0.f;S2=0.f;S3=0.f;S4=0.f;S5=0.f;S6=0.f;S7=0.f;           \
      if (Lq < 2) {                                                      \
        S0 = *(const f4u*)(xp0 + (KN)); S1 = *(const f4u*)(xp1 + (KN));  \
        S2 = *(const f4u*)(xp2 + (KN)); S3 = *(const f4u*)(xp3 + (KN));  \
        S4 = *(const f4u*)(xp4 + (KN)); S5 = *(const f4u*)(xp5 + (KN));  \
        S6 = *(const f4u*)(xp6 + (KN)); S7 = *(const f4u*)(xp7 + (KN));  \
      } else if (Lq == 2) {                                              \
        S0[0] = xp0[(KN)]; S1[0] = xp1[(KN)];                            \
        S2[0] = xp2[(KN)]; S3[0] = xp3[(KN)];                            \
        S4[0] = xp4[(KN)]; S5[0] = xp5[(KN)];                            \
        S6[0] = xp6[(KN)]; S7[0] = xp7[(KN)];                            \
      }                                                                  \
    } }

#define WRITE_SET(S0,S1,S2,S3,S4,S5,S6,S7)                               \
  { *(f4*)(xbw + 0*16*SXS) = S0; *(f4*)(xbw + 1*16*SXS) = S1;            \
    *(f4*)(xbw + 2*16*SXS) = S2; *(f4*)(xbw + 3*16*SXS) = S3;            \
    *(f4*)(xbw + 4*16*SXS) = S4; *(f4*)(xbw + 5*16*SXS) = S5;            \
    *(f4*)(xbw + 6*16*SXS) = S6; *(f4*)(xbw + 7*16*SXS) = S7; }

// j-split FMA: 4 granules; per granule read 8 x-f4 (rows rg+16i, 4-way jq
// broadcast) + 4 W-f4 (own jq, 16-way broadcast), 32 f4-FMAs.
#define RFMA(CC)                                                         \
  { const float* wb = wjq + (CC) * (TK * NH);                            \
    _Pragma("unroll")                                                    \
    for (int g = 0; g < 4; ++g) {                                        \
      f4 x0 = *(const f4*)(xrd + 0*16*SXS + g*4);                        \
      f4 x1 = *(const f4*)(xrd + 1*16*SXS + g*4);                        \
      f4 x2 = *(const f4*)(xrd + 2*16*SXS + g*4);                        \
      f4 x3 = *(const f4*)(xrd + 3*16*SXS + g*4);                        \
      f4 x4 = *(const f4*)(xrd + 4*16*SXS + g*4);                        \
      f4 x5 = *(const f4*)(xrd + 5*16*SXS + g*4);                        \
      f4 x6 = *(const f4*)(xrd + 6*16*SXS + g*4);                        \
      f4 x7 = *(const f4*)(xrd + 7*16*SXS + g*4);                        \
      f4 w0v = *(const f4*)(wb + (g*4+0)*NH);                            \
      f4 w1v = *(const f4*)(wb + (g*4+1)*NH);                            \
      f4 w2v = *(const f4*)(wb + (g*4+2)*NH);                            \
      f4 w3v = *(const f4*)(wb + (g*4+3)*NH);                            \
      acc0 += x0[0]*w0v; acc0 += x0[1]*w1v; acc0 += x0[2]*w2v; acc0 += x0[3]*w3v; \
      acc1 += x1[0]*w0v; acc1 += x1[1]*w1v; acc1 += x1[2]*w2v; acc1 += x1[3]*w3v; \
      acc2 += x2[0]*w0v; acc2 += x2[1]*w1v; acc2 += x2[2]*w2v; acc2 += x2[3]*w3v; \
      acc3 += x3[0]*w0v; acc3 += x3[1]*w1v; acc3 += x3[2]*w2v; acc3 += x3[3]*w3v; \
      acc4 += x4[0]*w0v; acc4 += x4[1]*w1v; acc4 += x4[2]*w2v; acc4 += x4[3]*w3v; \
      acc5 += x5[0]*w0v; acc5 += x5[1]*w1v; acc5 += x5[2]*w2v; acc5 += x5[3]*w3v; \
      acc6 += x6[0]*w0v; acc6 += x6[1]*w1v; acc6 += x6[2]*w2v; acc6 += x6[3]*w3v; \
      acc7 += x7[0]*w0v; acc7 += x7[1]*w1v; acc7 += x7[2]*w2v; acc7 += x7[3]*w3v; \
    } }

__global__ __launch_bounds__(256)
void k_gemm1(const float* __restrict__ X, const float* __restrict__ W1,
             float* __restrict__ hpart) {
    __shared__ float wlds[RW * NH];                 // 10240 B
    __shared__ float sX[4][TILE_R * SXS];           // 4 x 10240 B
    const int wid = threadIdx.x >> 6;
    const int t   = threadIdx.x & 63;
    const int rb    = blockIdx.x % NRBV;
    const int split = blockIdx.x / NRBV;

    {
        const f4* W1v = (const f4*)W1;              // each W1 row = 4 f4
        const int wbase = split * RW;
#pragma unroll
        for (int r = 0; r < 3; ++r) {               // ceil(640/256) = 3 iters
            int idx = r * 256 + threadIdx.x;        // f4 index into wlds
            if (idx < RW * 4) {
                int krow = wbase + (idx >> 2);
                f4 wv = 0.f;
                if (krow < K_IN) wv = W1v[krow * 4 + (idx & 3)];
                ((f4*)wlds)[idx] = wv;
            }
        }
    }
    __syncthreads();

    const int tile = rb * 4 + wid;
    if (tile >= NTILEV) return;                     // wave-uniform, after sync
    const int base = tile * TILE_R;
    const int Lq = t & 3;                           // 16B granule within 64B
    const int Lr = t >> 2;                          // row group 0..15

    const float* xp0 = X + (size_t)min(base + Lr +   0, N_NODES - 1) * K_IN + 4 * Lq;
    const float* xp1 = X + (size_t)min(base + Lr +  16, N_NODES - 1) * K_IN + 4 * Lq;
    const float* xp2 = X + (size_t)min(base + Lr +  32, N_NODES - 1) * K_IN + 4 * Lq;
    const float* xp3 = X + (size_t)min(base + Lr +  48, N_NODES - 1) * K_IN + 4 * Lq;
    const float* xp4 = X + (size_t)min(base + Lr +  64, N_NODES - 1) * K_IN + 4 * Lq;
    const float* xp5 = X + (size_t)min(base + Lr +  80, N_NODES - 1) * K_IN + 4 * Lq;
    const float* xp6 = X + (size_t)min(base + Lr +  96, N_NODES - 1) * K_IN + 4 * Lq;
    const float* xp7 = X + (size_t)min(base + Lr + 112, N_NODES - 1) * K_IN + 4 * Lq;

    float* xbuf = sX[wid];
    float* xbw  = xbuf + Lr * SXS + 4 * Lq;         // stage write base

    // compute-side roles: rg = row-group (reuses Lr), jq = j-quad (reuses Lq)
    const float* xrd = xbuf + Lr * SXS;             // rows Lr + 16i
    const float* wjq = wlds + Lq * 4;               // own j-quad column

    f4 acc0 = 0.f, acc1 = 0.f, acc2 = 0.f, acc3 = 0.f;
    f4 acc4 = 0.f, acc5 = 0.f, acc6 = 0.f, acc7 = 0.f;

    f4 sP0, sP1, sP2, sP3, sP4, sP5, sP6, sP7;      // named stage sets
    f4 sQ0, sQ1, sQ2, sQ3, sQ4, sQ5, sQ6, sQ7;

    const int k0 = split * RW;                      // first k of this split
    LOADG(k0, sP0, sP1, sP2, sP3, sP4, sP5, sP6, sP7)

#pragma unroll 1
    for (int j = 0; j < CPS / 2; ++j) {
        const int ke = k0 + 2 * j * TK;             // even chunk k-offset
        WRITE_SET(sP0, sP1, sP2, sP3, sP4, sP5, sP6, sP7)
        LOADG(ke + TK, sQ0, sQ1, sQ2, sQ3, sQ4, sQ5, sQ6, sQ7)
        __builtin_amdgcn_wave_barrier();
        RFMA(2 * j)
        __builtin_amdgcn_wave_barrier();
        WRITE_SET(sQ0, sQ1, sQ2, sQ3, sQ4, sQ5, sQ6, sQ7)
        if (j + 1 < CPS / 2) {
            LOADG(ke + 2 * TK, sP0, sP1, sP2, sP3, sP4, sP5, sP6, sP7)
        }
        __builtin_amdgcn_wave_barrier();
        RFMA(2 * j + 1)
        __builtin_amdgcn_wave_barrier();
    }

    // coalesced store: lane (rg,jq) writes f4 jq of rows base+rg+16i
    const size_t sb = (size_t)split * N_NODES;
    float* op = hpart + (sb + base + Lr) * NH + Lq * 4;
#define STORE_ACC(I, A)                                                  \
    if (base + Lr + 16 * (I) < N_NODES)                                  \
        *(f4*)(op + (size_t)(16 * (I)) * NH) = A;
    STORE_ACC(0, acc0) STORE_ACC(1, acc1) STORE_ACC(2, acc2) STORE_ACC(3, acc3)
    STORE_ACC(4, acc4) STORE_ACC(5, acc5) STORE_ACC(6, acc6) STORE_ACC(7, acc7)
#undef STORE_ACC
}

// ---------------- K3: h = norm_src * sum_s hpart[s] ----------------
__global__ __launch_bounds__(256)
void k_reduce(const float* __restrict__ hpart, const int* __restrict__ deg_out,
              float* __restrict__ h) {
    int idx = blockIdx.x * 256 + threadIdx.x;   // f4 index
    if (idx >= N_NODES * 4) return;
    f4 a = 0.f;
#pragma unroll
    for (int s = 0; s < KSPLIT; ++s)
        a += ((const f4*)hpart)[(size_t)s * N_NODES * 4 + idx];
    float ns = rsqrtf((float)max(deg_out[idx >> 2], 1));
    ((f4*)h)[idx] = a * ns;
}

// ---------------- K4: gather layer1 + relu + fused (.. @ W2) ----------------
__global__ __launch_bounds__(256)
void k_layer1(const float* __restrict__ h, const int* __restrict__ adj,
              const int* __restrict__ cnt, const int* __restrict__ deg_out,
              const float* __restrict__ W2, const float* __restrict__ b1,
              float* __restrict__ g) {
    const int lane = threadIdx.x & 63;
    const int wid  = threadIdx.x >> 6;
    const int d    = blockIdx.x * 4 + wid;
    if (d >= N_NODES) return;                  // wave-uniform
    const int j4 = lane & 3, slot = lane >> 2;
    const int start = d * SLOT;
    const int deg   = min(cnt[d], SLOT);
    const int end   = start + deg;
    f4 agg = 0.f;
    for (int p = start + slot; p < end; p += 16) {
        int s = adj[p];
        agg += ((const f4*)h)[s * 4 + j4];
    }
#pragma unroll
    for (int off = 4; off < 64; off <<= 1) {
        agg[0] += __shfl_xor(agg[0], off);
        agg[1] += __shfl_xor(agg[1], off);
        agg[2] += __shfl_xor(agg[2], off);
        agg[3] += __shfl_xor(agg[3], off);
    }
    __shared__ float st[4][NH];
    const float nd = rsqrtf((float)max(deg, 1));
    if (slot == 0) {
        f4 bb = ((const f4*)b1)[j4];
        f4 tj;
        tj[0] = fmaxf(fmaf(agg[0], nd, bb[0]), 0.f);
        tj[1] = fmaxf(fmaf(agg[1], nd, bb[1]), 0.f);
        tj[2] = fmaxf(fmaf(agg[2], nd, bb[2]), 0.f);
        tj[3] = fmaxf(fmaf(agg[3], nd, bb[3]), 0.f);
        ((f4*)st[wid])[j4] = tj;
    }
    __builtin_amdgcn_wave_barrier();
    float r = 0.f;
    if (lane < NO) {
#pragma unroll
        for (int qq = 0; qq < NH; ++qq)
            r = fmaf(st[wid][qq], W2[qq * NO + lane], r);
    }
    if (lane < 8) {
        float ns = rsqrtf((float)max(deg_out[d], 1));
        g[(size_t)d * 8 + lane] = (lane < NO) ? ns * r : 0.f;  // zero pad slot
    }
}

// ---------------- K5: gather layer2 -> out ----------------
__global__ __launch_bounds__(256)
void k_layer2(const float* __restrict__ g, const int* __restrict__ adj,
              const int* __restrict__ cnt, const float* __restrict__ b2,
              float* __restrict__ out) {
    const int lane = threadIdx.x & 63;
    const int wid  = threadIdx.x >> 6;
    const int d    = blockIdx.x * 4 + wid;
    if (d >= N_NODES) return;
    const int o4 = lane & 1, slot = lane >> 1;
    const int start = d * SLOT;
    const int deg   = min(cnt[d], SLOT);
    const int end   = start + deg;
    f4 agg = 0.f;
    for (int p = start + slot; p < end; p += 32) {
        int s = adj[p];
        agg += ((const f4*)g)[s * 2 + o4];
    }
#pragma unroll
    for (int off = 2; off < 64; off <<= 1) {
        agg[0] += __shfl_xor(agg[0], off);
        agg[1] += __shfl_xor(agg[1], off);
        agg[2] += __shfl_xor(agg[2], off);
        agg[3] += __shfl_xor(agg[3], off);
    }
    // even lanes hold o=0..3 sums, odd lanes hold o=4..7 sums
    const int sl = lane >> 2;
    float v0 = __shfl(agg[0], sl);
    float v1 = __shfl(agg[1], sl);
    float v2 = __shfl(agg[2], sl);
    float v3 = __shfl(agg[3], sl);
    int cm = lane & 3;
    float v = (cm == 0) ? v0 : (cm == 1) ? v1 : (cm == 2) ? v2 : v3;
    if (lane < NO) {
        float nd = rsqrtf((float)max(deg, 1));
        out[(size_t)d * NO + lane] = fmaf(v, nd, b2[lane]);
    }
}

extern "C" void kernel_launch(void* const* d_in, const int* in_sizes, int n_in,
                              void* d_out, int out_size, void* d_ws, size_t ws_size,
                              hipStream_t stream) {
    const float* X   = (const float*)d_in[0];
    const int*   src = (const int*)d_in[1];
    const int*   dst = (const int*)d_in[2];
    const float* W1  = (const float*)d_in[3];
    const float* b1  = (const float*)d_in[4];
    const float* W2  = (const float*)d_in[5];
    const float* b2  = (const float*)d_in[6];
    float* out = (float*)d_out;

    char* w = (char*)d_ws;
    float* hpart    = (float*)w;  w += (size_t)KSPLIT * N_NODES * NH * 4; // 57.6 MB
    float* h        = (float*)w;  w += (size_t)N_NODES * NH * 4;          // 6.4 MB
    float* g        = (float*)w;  w += (size_t)N_NODES * 8 * 4;           // 3.2 MB
    int*   adj      = (int*)w;    w += (size_t)N_NODES * SLOT * 4;        // 38.4 MB
    int*   deg_out_a= (int*)w;    w += (size_t)N_NODES * 4;
    int*   cnt      = (int*)w;    w += (size_t)N_NODES * 4;
    int2*  ebuf     = (int2*)w;   w += (size_t)N_EDGES * 8;               // 25.6 MB
    int*   sbuf     = (int*)w;    w += (size_t)N_EDGES * 4;               // 12.8 MB
    int*   partial_d= (int*)w;    w += (size_t)SBLK * NBKT * 4;           // 512 KB
    int*   partial_s= (int*)w;    w += (size_t)SBLK * NBKT * 4;
    int*   pbase_d  = (int*)w;    w += (size_t)SBLK * NBKT * 4;
    int*   pbase_s  = (int*)w;    w += (size_t)SBLK * NBKT * 4;
    int*   btot_d   = (int*)w;    w += NBKT * 4;
    int*   btot_s   = (int*)w;    w += NBKT * 4;
    int*   bbase_d  = (int*)w;    w += NBKT * 4;
    int*   bbase_s  = (int*)w;    w += NBKT * 4;

    // ---- atomic-free graph build (counting sort by 391-node buckets) ----
    k_pcount   <<<SBLK, 256, 0, stream>>>(dst, partial_d);
    k_pcount   <<<SBLK, 256, 0, stream>>>(src, partial_s);
    k_colscan  <<<NBKT, 256, 0, stream>>>(partial_d, pbase_d, btot_d);
    k_colscan  <<<NBKT, 256, 0, stream>>>(partial_s, pbase_s, btot_s);
    k_basescan <<<1,    256, 0, stream>>>(btot_d, bbase_d, btot_s, bbase_s);
    k_pscatter2<<<SBLK, 256, 0, stream>>>(src, dst, pbase_d, bbase_d, ebuf);
    k_pscatter1<<<SBLK, 256, 0, stream>>>(src, pbase_s, bbase_s, sbuf);
    k_adj      <<<NBKT, 512, 0, stream>>>(ebuf, bbase_d, btot_d, adj, cnt);
    k_hist     <<<NBKT, 512, 0, stream>>>(sbuf, bbase_s, btot_s, deg_out_a);

    // ---- GCN pipeline ----
    k_gemm1 <<<NRBV * KSPLIT, 256, 0, stream>>>(X, W1, hpart);
    k_reduce<<<(N_NODES * 4 + 255) / 256, 256, 0, stream>>>(hpart, deg_out_a, h);
    k_layer1<<<(N_NODES + 3) / 4, 256, 0, stream>>>(h, adj, cnt, deg_out_a,
                                                    W2, b1, g);
    k_layer2<<<(N_NODES + 3) / 4, 256, 0, stream>>>(g, adj, cnt, b2, out);
}